// Round 8
// baseline (356.780 us; speedup 1.0000x reference)
//
#include <hip/hip_runtime.h>

#define HOUT 15
#define WOUT 15
// input  (32, 32, 32, 32, 16)  fp32
// ncv    (32, 32, 15, 15, 16)  fp32
// w      (3, 3, 32, 4, 4, 32)  fp32
// out    (32, 32, 15, 15, 16)  fp32

typedef float v2 __attribute__((ext_vector_type(2)));

// DPP butterfly add step (ctrl must be a literal). Compiler-generated DPP
// gets its hazard NOPs inserted automatically — verified correct rounds 1-4.
// (Hand-rolled v_permlane*_swap asm failed rounds 5-7: no hazard protection
// inside inline asm + uncertain two-output semantics. Benched.)
#define DPP_ADDF(x, ctrl) \
    ((x) + __builtin_bit_cast(float, __builtin_amdgcn_update_dpp( \
        0, __builtin_bit_cast(int, (x)), (ctrl), 0xF, 0xF, true)))

// ---------------- pass 0: repack w for the (m, d-half) lane mapping --------
// w[kl][n][x][d][m] -> w3[n][kl][xq][l64][e]  (147456 floats = 576 KB)
// lane l64 = m + 32*half owns d in {2*half, 2*half+1}. Element e of quad xq:
//   x = 2*xq + (e>>1), d = 2*half + (e&1)
__global__ __launch_bounds__(256) void prep_w(const float* __restrict__ wt,
                                              float* __restrict__ w3)
{
    const int t   = blockIdx.x * 256 + threadIdx.x;   // 0..147455
    const int e   = t & 3;
    const int l64 = (t >> 2) & 63;
    const int xq  = (t >> 8) & 1;
    const int r   = t >> 9;          // n*9 + kl
    const int kl  = r % 9;
    const int n   = r / 9;
    const int mm  = l64 & 31;
    const int hf  = l64 >> 5;
    const int x   = 2 * xq + (e >> 1);
    const int d   = 2 * hf + (e & 1);
    w3[t] = wt[((kl * 32 + n) * 16 + x * 4 + d) * 32 + mm];
}

// ---------------- fused kernel: one wave per output position ---------------
// lane = m + 32*half; half owns d-pair {2h, 2h+1}. av wave-uniform -> SGPRs.
// Depth-1 register prefetch of next site's w quads + av hides VMEM/SMEM
// latency behind the current site's compute. Cross-lane ops are the
// round-4-verified shfl_xor / DPP / ds_swizzle set.
// NOTE: no min-waves clause (round 2: forced cap -> spill -> 3.4x regression).
__global__ __launch_bounds__(256) void caps_all(
    const float* __restrict__ input,
    const float* __restrict__ ncv,
    const float* __restrict__ w3,
    const float* __restrict__ gamma,
    const float* __restrict__ beta,
    float* __restrict__ out)
{
    const int tid  = threadIdx.x;
    const int l64  = tid & 63;
    const int m    = l64 & 31;
    const int half = l64 >> 5;

    // wave-uniform position -> force into SGPRs so av loads go scalar
    const int posu = __builtin_amdgcn_readfirstlane(blockIdx.x * 4 + (tid >> 6));
    const int b  = posu / (HOUT * WOUT);
    const int hw = posu % (HOUT * WOUT);
    const int h  = hw / WOUT;
    const int wo = hw % WOUT;

    // input[b][n][h][w][16]: strides 524288 / 16384 / 512 / 16
    const float* ipb = input + (size_t)b * 524288 + (h * 2) * 512 + (wo * 2) * 16;

    // cv = ncv[b][m][h][wo][a*4 + 2*half + {0,1}], pre-scaled by 0.25*log2e
    const float* cvp = ncv + (((size_t)b * 32 + m) * (HOUT * WOUT) + hw) * 16 + 2 * half;
    const float SC = 0.36067376022224085f;   // 0.25 * log2(e)
    v2 sc2 = {SC, SC};
    v2 cv0 = *(const v2*)(cvp +  0) * sc2;
    v2 cv1 = *(const v2*)(cvp +  4) * sc2;
    v2 cv2 = *(const v2*)(cvp +  8) * sc2;
    v2 cv3 = *(const v2*)(cvp + 12) * sc2;

    v2 acc0 = {0.f, 0.f}, acc1 = {0.f, 0.f}, acc2 = {0.f, 0.f}, acc3 = {0.f, 0.f};

    // site pointer into w3 (advances 512 floats per site, 288 sites total;
    // prefetch reads <=3 KB past the end -> lands in the large workspace)
    const float* wp = w3 + l64 * 4;

    // prologue: site (n=0, kl=0)
    float4 q0 = *(const float4*)(wp);
    float4 q1 = *(const float4*)(wp + 256);
    float4 a0 = *(const float4*)(ipb + 0);
    float4 a1 = *(const float4*)(ipb + 4);
    float4 a2 = *(const float4*)(ipb + 8);
    float4 a3 = *(const float4*)(ipb + 12);

    for (int n = 0; n < 32; ++n) {
#pragma unroll
        for (int kl = 0; kl < 9; ++kl) {
            // ---- issue next-site prefetch (depth 1) ----
            const int nkl = (kl == 8) ? 0 : kl + 1;              // static
            const int nn  = (kl == 8) ? ((n + 1) & 31) : n;      // uniform
            const float* nap = ipb + nn * 16384
                             + (nkl / 3) * 512 + (nkl % 3) * 16;
            float4 na0 = *(const float4*)(nap + 0);
            float4 na1 = *(const float4*)(nap + 4);
            float4 na2 = *(const float4*)(nap + 8);
            float4 na3 = *(const float4*)(nap + 12);
            const float* nwp = wp + 512;
            float4 nq0 = *(const float4*)(nwp);
            float4 nq1 = *(const float4*)(nwp + 256);

            // ---- compute current site ----
            const v2 wx0 = {q0.x, q0.y}, wx1 = {q0.z, q0.w};
            const v2 wx2 = {q1.x, q1.y}, wx3 = {q1.z, q1.w};

            v2 u0 = (v2){a0.x, a0.x} * wx0;
            u0 = __builtin_elementwise_fma((v2){a0.y, a0.y}, wx1, u0);
            u0 = __builtin_elementwise_fma((v2){a0.z, a0.z}, wx2, u0);
            u0 = __builtin_elementwise_fma((v2){a0.w, a0.w}, wx3, u0);
            v2 u1 = (v2){a1.x, a1.x} * wx0;
            u1 = __builtin_elementwise_fma((v2){a1.y, a1.y}, wx1, u1);
            u1 = __builtin_elementwise_fma((v2){a1.z, a1.z}, wx2, u1);
            u1 = __builtin_elementwise_fma((v2){a1.w, a1.w}, wx3, u1);
            v2 u2 = (v2){a2.x, a2.x} * wx0;
            u2 = __builtin_elementwise_fma((v2){a2.y, a2.y}, wx1, u2);
            u2 = __builtin_elementwise_fma((v2){a2.z, a2.z}, wx2, u2);
            u2 = __builtin_elementwise_fma((v2){a2.w, a2.w}, wx3, u2);
            v2 u3 = (v2){a3.x, a3.x} * wx0;
            u3 = __builtin_elementwise_fma((v2){a3.y, a3.y}, wx1, u3);
            u3 = __builtin_elementwise_fma((v2){a3.z, a3.z}, wx2, u3);
            u3 = __builtin_elementwise_fma((v2){a3.w, a3.w}, wx3, u3);

            // this half's 8 terms of the scaled logit
            v2 ds = u0 * cv0;
            ds = __builtin_elementwise_fma(u1, cv1, ds);
            ds = __builtin_elementwise_fma(u2, cv2, ds);
            ds = __builtin_elementwise_fma(u3, cv3, ds);
            float part = ds.x + ds.y;
            float lg   = part + __shfl_xor(part, 32, 64);  // + other half
            float e1   = __builtin_exp2f(lg);

            // softmax denom over 32 m's: 4 DPP adds + ds_swizzle xor16
            float s = e1;
            s = DPP_ADDF(s, 0xB1);    // xor1  (quad_perm [1,0,3,2])
            s = DPP_ADDF(s, 0x4E);    // xor2  (quad_perm [2,3,0,1])
            s = DPP_ADDF(s, 0x141);   // xor4  (row_half_mirror)
            s = DPP_ADDF(s, 0x140);   // xor8  (row_mirror)
            s += __builtin_bit_cast(float,
                  __builtin_amdgcn_ds_swizzle(__builtin_bit_cast(int, s), 0x401F)); // xor16

            float p = e1 * __builtin_amdgcn_rcpf(s);
            v2 p2 = {p, p};
            acc0 = __builtin_elementwise_fma(p2, u0, acc0);
            acc1 = __builtin_elementwise_fma(p2, u1, acc1);
            acc2 = __builtin_elementwise_fma(p2, u2, acc2);
            acc3 = __builtin_elementwise_fma(p2, u3, acc3);

            // ---- rotate prefetch ----
            a0 = na0; a1 = na1; a2 = na2; a3 = na3;
            q0 = nq0; q1 = nq1;
            wp = nwp;
        }
    }

    // ---- fused LayerNorm: 8 local + cross-half exchange (shfl_xor 32) ----
    v2 s2 = (acc0 + acc1) + (acc2 + acc3);
    float s8  = s2.x + s2.y;
    float s16 = s8 + __shfl_xor(s8, 32, 64);
    float mu  = s16 * 0.0625f;
    v2 mv = {mu, mu};

    v2 vv = {0.f, 0.f};
    v2 t0 = acc0 - mv; vv = __builtin_elementwise_fma(t0, t0, vv);
    v2 t1 = acc1 - mv; vv = __builtin_elementwise_fma(t1, t1, vv);
    v2 t2 = acc2 - mv; vv = __builtin_elementwise_fma(t2, t2, vv);
    v2 t3 = acc3 - mv; vv = __builtin_elementwise_fma(t3, t3, vv);
    float v8  = vv.x + vv.y;
    float v16 = v8 + __shfl_xor(v8, 32, 64);
    float rstd = __builtin_amdgcn_rsqf(v16 * 0.0625f + 1e-5f);
    v2 rs2 = {rstd, rstd};

    const int db = 2 * half;
    float* op = out + (((size_t)b * 32 + m) * (HOUT * WOUT) + hw) * 16 + db;
    {
        v2 g  = *(const v2*)(gamma + 0 + db);
        v2 be = *(const v2*)(beta  + 0 + db);
        *(v2*)(op + 0)  = __builtin_elementwise_fma(t0 * rs2, g, be);
    }
    {
        v2 g  = *(const v2*)(gamma + 4 + db);
        v2 be = *(const v2*)(beta  + 4 + db);
        *(v2*)(op + 4)  = __builtin_elementwise_fma(t1 * rs2, g, be);
    }
    {
        v2 g  = *(const v2*)(gamma + 8 + db);
        v2 be = *(const v2*)(beta  + 8 + db);
        *(v2*)(op + 8)  = __builtin_elementwise_fma(t2 * rs2, g, be);
    }
    {
        v2 g  = *(const v2*)(gamma + 12 + db);
        v2 be = *(const v2*)(beta  + 12 + db);
        *(v2*)(op + 12) = __builtin_elementwise_fma(t3 * rs2, g, be);
    }
}

extern "C" void kernel_launch(void* const* d_in, const int* in_sizes, int n_in,
                              void* d_out, int out_size, void* d_ws, size_t ws_size,
                              hipStream_t stream) {
    const float* input = (const float*)d_in[0];
    const float* ncv   = (const float*)d_in[1];
    const float* wt    = (const float*)d_in[2];
    const float* gamma = (const float*)d_in[3];
    const float* beta  = (const float*)d_in[4];
    float* out = (float*)d_out;
    float* w3  = (float*)d_ws;   // 576 KB + tail pad (prefetch overread)

    prep_w<<<dim3(576), dim3(256), 0, stream>>>(wt, w3);
    caps_all<<<dim3(1800), dim3(256), 0, stream>>>(input, ncv, w3, gamma, beta, out);
}

// Round 9
// 338.413 us; speedup vs baseline: 1.0543x; 1.0543x over previous
//
#include <hip/hip_runtime.h>

#define HOUT 15
#define WOUT 15
// input  (32, 32, 32, 32, 16)  fp32
// ncv    (32, 32, 15, 15, 16)  fp32
// w      (3, 3, 32, 4, 4, 32)  fp32
// out    (32, 32, 15, 15, 16)  fp32

typedef float v2 __attribute__((ext_vector_type(2)));

// DPP butterfly add step (ctrl must be a literal). Compiler-generated DPP
// gets hazard NOPs inserted automatically — verified correct rounds 1-4, 8.
#define DPP_ADDF(x, ctrl) \
    ((x) + __builtin_bit_cast(float, __builtin_amdgcn_update_dpp( \
        0, __builtin_bit_cast(int, (x)), (ctrl), 0xF, 0xF, true)))

// ---------------- pass 0: repack w for the (m, d-half) lane mapping --------
// w[kl][n][x][d][m] -> w3[n][kl][xq][l64][e]  (147456 floats = 576 KB)
// lane l64 = m + 32*half owns d in {2*half, 2*half+1}. Element e of quad xq:
//   x = 2*xq + (e>>1), d = 2*half + (e&1)
__global__ __launch_bounds__(256) void prep_w(const float* __restrict__ wt,
                                              float* __restrict__ w3)
{
    const int t   = blockIdx.x * 256 + threadIdx.x;   // 0..147455
    const int e   = t & 3;
    const int l64 = (t >> 2) & 63;
    const int xq  = (t >> 8) & 1;
    const int r   = t >> 9;          // n*9 + kl
    const int kl  = r % 9;
    const int n   = r / 9;
    const int mm  = l64 & 31;
    const int hf  = l64 >> 5;
    const int x   = 2 * xq + (e >> 1);
    const int d   = 2 * hf + (e & 1);
    w3[t] = wt[((kl * 32 + n) * 16 + x * 4 + d) * 32 + mm];
}

// ---------------- fused kernel: one wave per output position ---------------
// lane = m + 32*half; half owns d-pair {2h, 2h+1}. av wave-uniform -> SGPRs.
// TWO independent site streams per wave (A: n=0..15, B: n=16..31) overlap
// their latency chains (SMEM wait, shfl/swizzle LDS round-trips, exp chain):
// while A stalls, B issues. Separate accumulators, merged in the epilogue.
// NOTE: no min-waves clause (round 2: forced cap -> spill -> 3.4x regression).
__global__ __launch_bounds__(256) void caps_all(
    const float* __restrict__ input,
    const float* __restrict__ ncv,
    const float* __restrict__ w3,
    const float* __restrict__ gamma,
    const float* __restrict__ beta,
    float* __restrict__ out)
{
    const int tid  = threadIdx.x;
    const int l64  = tid & 63;
    const int m    = l64 & 31;
    const int half = l64 >> 5;

    // wave-uniform position -> force into SGPRs so av loads go scalar
    const int posu = __builtin_amdgcn_readfirstlane(blockIdx.x * 4 + (tid >> 6));
    const int b  = posu / (HOUT * WOUT);
    const int hw = posu % (HOUT * WOUT);
    const int h  = hw / WOUT;
    const int wo = hw % WOUT;

    // input[b][n][h][w][16]: strides 524288 / 16384 / 512 / 16
    const float* ipb = input + (size_t)b * 524288 + (h * 2) * 512 + (wo * 2) * 16;

    // cv = ncv[b][m][h][wo][a*4 + 2*half + {0,1}], pre-scaled by 0.25*log2e
    const float* cvp = ncv + (((size_t)b * 32 + m) * (HOUT * WOUT) + hw) * 16 + 2 * half;
    const float SC = 0.36067376022224085f;   // 0.25 * log2(e)
    v2 sc2 = {SC, SC};
    v2 cv0 = *(const v2*)(cvp +  0) * sc2;
    v2 cv1 = *(const v2*)(cvp +  4) * sc2;
    v2 cv2 = *(const v2*)(cvp +  8) * sc2;
    v2 cv3 = *(const v2*)(cvp + 12) * sc2;

    v2 acA0 = {0.f,0.f}, acA1 = {0.f,0.f}, acA2 = {0.f,0.f}, acA3 = {0.f,0.f};
    v2 acB0 = {0.f,0.f}, acB1 = {0.f,0.f}, acB2 = {0.f,0.f}, acB3 = {0.f,0.f};

    // u[a] = sum_x av[a,x] * w[x, dpair, m] for one site
    auto site_u = [&](const float4& A0, const float4& A1,
                      const float4& A2, const float4& A3,
                      const float4& Q0, const float4& Q1,
                      v2& U0, v2& U1, v2& U2, v2& U3) {
        const v2 W0 = {Q0.x, Q0.y}, W1 = {Q0.z, Q0.w};
        const v2 W2 = {Q1.x, Q1.y}, W3 = {Q1.z, Q1.w};
        U0 = (v2){A0.x, A0.x} * W0;
        U0 = __builtin_elementwise_fma((v2){A0.y, A0.y}, W1, U0);
        U0 = __builtin_elementwise_fma((v2){A0.z, A0.z}, W2, U0);
        U0 = __builtin_elementwise_fma((v2){A0.w, A0.w}, W3, U0);
        U1 = (v2){A1.x, A1.x} * W0;
        U1 = __builtin_elementwise_fma((v2){A1.y, A1.y}, W1, U1);
        U1 = __builtin_elementwise_fma((v2){A1.z, A1.z}, W2, U1);
        U1 = __builtin_elementwise_fma((v2){A1.w, A1.w}, W3, U1);
        U2 = (v2){A2.x, A2.x} * W0;
        U2 = __builtin_elementwise_fma((v2){A2.y, A2.y}, W1, U2);
        U2 = __builtin_elementwise_fma((v2){A2.z, A2.z}, W2, U2);
        U2 = __builtin_elementwise_fma((v2){A2.w, A2.w}, W3, U2);
        U3 = (v2){A3.x, A3.x} * W0;
        U3 = __builtin_elementwise_fma((v2){A3.y, A3.y}, W1, U3);
        U3 = __builtin_elementwise_fma((v2){A3.z, A3.z}, W2, U3);
        U3 = __builtin_elementwise_fma((v2){A3.w, A3.w}, W3, U3);
    };

    // logit partial -> softmax weight p (verified cross-lane set: shfl/DPP/swz)
    auto site_p = [&](v2 U0, v2 U1, v2 U2, v2 U3) -> float {
        v2 ds = U0 * cv0;
        ds = __builtin_elementwise_fma(U1, cv1, ds);
        ds = __builtin_elementwise_fma(U2, cv2, ds);
        ds = __builtin_elementwise_fma(U3, cv3, ds);
        float part = ds.x + ds.y;
        float lg   = part + __shfl_xor(part, 32, 64);  // + other half's terms
        float e1   = __builtin_exp2f(lg);
        float s = e1;
        s = DPP_ADDF(s, 0xB1);    // xor1  (quad_perm [1,0,3,2])
        s = DPP_ADDF(s, 0x4E);    // xor2  (quad_perm [2,3,0,1])
        s = DPP_ADDF(s, 0x141);   // xor4  (row_half_mirror)
        s = DPP_ADDF(s, 0x140);   // xor8  (row_mirror)
        s += __builtin_bit_cast(float,
              __builtin_amdgcn_ds_swizzle(__builtin_bit_cast(int, s), 0x401F)); // xor16
        return e1 * __builtin_amdgcn_rcpf(s);
    };

    // stream A walks sites (n=0..15)x(kl=0..8); stream B = A + 16 capsules
    const float* wp = w3 + l64 * 4;          // advances 512 floats/site
    // B offsets: +16*16384 floats in input, +16*9*512 = 73728 floats in w3

    for (int n = 0; n < 16; ++n) {
#pragma unroll
        for (int kl = 0; kl < 9; ++kl) {
            const float* apA = ipb + n * 16384 + (kl / 3) * 512 + (kl % 3) * 16;
            const float* apB = apA + 262144;

            const float4 aA0 = *(const float4*)(apA + 0);
            const float4 aA1 = *(const float4*)(apA + 4);
            const float4 aA2 = *(const float4*)(apA + 8);
            const float4 aA3 = *(const float4*)(apA + 12);
            const float4 aB0 = *(const float4*)(apB + 0);
            const float4 aB1 = *(const float4*)(apB + 4);
            const float4 aB2 = *(const float4*)(apB + 8);
            const float4 aB3 = *(const float4*)(apB + 12);

            const float4 qA0 = *(const float4*)(wp);
            const float4 qA1 = *(const float4*)(wp + 256);
            const float4 qB0 = *(const float4*)(wp + 73728);
            const float4 qB1 = *(const float4*)(wp + 73728 + 256);

            v2 uA0, uA1, uA2, uA3, uB0, uB1, uB2, uB3;
            site_u(aA0, aA1, aA2, aA3, qA0, qA1, uA0, uA1, uA2, uA3);
            site_u(aB0, aB1, aB2, aB3, qB0, qB1, uB0, uB1, uB2, uB3);

            const float pA = site_p(uA0, uA1, uA2, uA3);
            const float pB = site_p(uB0, uB1, uB2, uB3);

            const v2 pA2 = {pA, pA};
            const v2 pB2 = {pB, pB};
            acA0 = __builtin_elementwise_fma(pA2, uA0, acA0);
            acA1 = __builtin_elementwise_fma(pA2, uA1, acA1);
            acA2 = __builtin_elementwise_fma(pA2, uA2, acA2);
            acA3 = __builtin_elementwise_fma(pA2, uA3, acA3);
            acB0 = __builtin_elementwise_fma(pB2, uB0, acB0);
            acB1 = __builtin_elementwise_fma(pB2, uB1, acB1);
            acB2 = __builtin_elementwise_fma(pB2, uB2, acB2);
            acB3 = __builtin_elementwise_fma(pB2, uB3, acB3);

            wp += 512;
        }
    }

    // merge streams
    v2 acc0 = acA0 + acB0;
    v2 acc1 = acA1 + acB1;
    v2 acc2 = acA2 + acB2;
    v2 acc3 = acA3 + acB3;

    // ---- fused LayerNorm: 8 local + cross-half exchange (shfl_xor 32) ----
    v2 s2 = (acc0 + acc1) + (acc2 + acc3);
    float s8  = s2.x + s2.y;
    float s16 = s8 + __shfl_xor(s8, 32, 64);
    float mu  = s16 * 0.0625f;
    v2 mv = {mu, mu};

    v2 vv = {0.f, 0.f};
    v2 t0 = acc0 - mv; vv = __builtin_elementwise_fma(t0, t0, vv);
    v2 t1 = acc1 - mv; vv = __builtin_elementwise_fma(t1, t1, vv);
    v2 t2 = acc2 - mv; vv = __builtin_elementwise_fma(t2, t2, vv);
    v2 t3 = acc3 - mv; vv = __builtin_elementwise_fma(t3, t3, vv);
    float v8  = vv.x + vv.y;
    float v16 = v8 + __shfl_xor(v8, 32, 64);
    float rstd = __builtin_amdgcn_rsqf(v16 * 0.0625f + 1e-5f);
    v2 rs2 = {rstd, rstd};

    const int db = 2 * half;
    float* op = out + (((size_t)b * 32 + m) * (HOUT * WOUT) + hw) * 16 + db;
    {
        v2 g  = *(const v2*)(gamma + 0 + db);
        v2 be = *(const v2*)(beta  + 0 + db);
        *(v2*)(op + 0)  = __builtin_elementwise_fma(t0 * rs2, g, be);
    }
    {
        v2 g  = *(const v2*)(gamma + 4 + db);
        v2 be = *(const v2*)(beta  + 4 + db);
        *(v2*)(op + 4)  = __builtin_elementwise_fma(t1 * rs2, g, be);
    }
    {
        v2 g  = *(const v2*)(gamma + 8 + db);
        v2 be = *(const v2*)(beta  + 8 + db);
        *(v2*)(op + 8)  = __builtin_elementwise_fma(t2 * rs2, g, be);
    }
    {
        v2 g  = *(const v2*)(gamma + 12 + db);
        v2 be = *(const v2*)(beta  + 12 + db);
        *(v2*)(op + 12) = __builtin_elementwise_fma(t3 * rs2, g, be);
    }
}

extern "C" void kernel_launch(void* const* d_in, const int* in_sizes, int n_in,
                              void* d_out, int out_size, void* d_ws, size_t ws_size,
                              hipStream_t stream) {
    const float* input = (const float*)d_in[0];
    const float* ncv   = (const float*)d_in[1];
    const float* wt    = (const float*)d_in[2];
    const float* gamma = (const float*)d_in[3];
    const float* beta  = (const float*)d_in[4];
    float* out = (float*)d_out;
    float* w3  = (float*)d_ws;                 // 576 KB

    prep_w<<<dim3(576), dim3(256), 0, stream>>>(wt, w3);
    caps_all<<<dim3(1800), dim3(256), 0, stream>>>(input, ncv, w3, gamma, beta, out);
}